// Round 6
// baseline (972.327 us; speedup 1.0000x reference)
//
#include <hip/hip_runtime.h>
#include <stdint.h>

constexpr int Bn = 8, Nn = 4096, Dn = 128, Cn = 256, Kn = 16;

// ---------------- Kernel A0: pack xyz -> float4 (x,y,z,xx), xx = ((x*x)+(y*y))+(z*z) exact ----------------
__global__ __launch_bounds__(256) void pack_kernel(const float* __restrict__ xyz, float4* __restrict__ xyzw)
{
    const int p = blockIdx.x * 256 + threadIdx.x;   // 32768 points
    const float x = xyz[p * 3 + 0], y = xyz[p * 3 + 1], z = xyz[p * 3 + 2];
    const float xx = __fadd_rn(__fadd_rn(__fmul_rn(x, x), __fmul_rn(y, y)), __fmul_rn(z, z));
    xyzw[p] = make_float4(x, y, z, xx);
}

// ---------------- Kernel A: exact KNN, fp32, two-pass threshold filter + bitonic pair-sort ----------------
// 4 query rows per wave (16 per block) amortize the candidate sweep 4x.
// Pass 1: approximate per-lane max of pd per query (threshold only).
// L = 16th-largest lane max (bitonic over lanes). Pass 2: recompute pd BIT-EXACTLY
// (pd = ((-xx_n) + 2*inner) - xx_m, inner = fma(z,z',fma(y,y',x*x')) -- the formula
// that passed rounds 3-5) and compact survivors (v >= L) to dense LDS via atomicAdd
// (placement order irrelevant: sort key (value desc, index asc) is a strict total
// order, indices unique). 21-step bitonic pair-sort leaves k-th neighbor in lane k.
// Safety: S>=16 <=> L <= exact 16th value <=> survivors contain the exact top-16.
// S<16 or S>64 (prob ~0) -> exhaustive recompute rescan (always correct).
__global__ __launch_bounds__(256) void knn_kernel(const float4* __restrict__ xyzw, int* __restrict__ idxout)
{
    __shared__ float dv[4][4][64];
    __shared__ int   di[4][4][64];
    __shared__ int   cnt[4][4];
    const int wave = threadIdx.x >> 6;
    const int lane = threadIdx.x & 63;
    const int rbase = blockIdx.x * 16 + wave * 4;      // 4 consecutive rows, same batch
    const float4* xb = xyzw + (size_t)(rbase >> 12) * Nn;
    const int n0 = rbase & (Nn - 1);

    float4 Q[4];
    float nxx[4];
#pragma unroll
    for (int q = 0; q < 4; ++q) { Q[q] = xb[n0 + q]; nxx[q] = -Q[q].w; }

    // ---- pass 1: per-lane max of (2*inner - xxm) per query (fast rounding OK) ----
    float m0[4], m1[4];
#pragma unroll
    for (int q = 0; q < 4; ++q) { m0[q] = -3.0e38f; m1[q] = -3.0e38f; }
    for (int i = 0; i < 64; i += 2) {
        const float4 Pa = xb[(i << 6) + lane];
        const float4 Pb = xb[((i + 1) << 6) + lane];
#pragma unroll
        for (int q = 0; q < 4; ++q) {
            const float ia = __builtin_fmaf(Q[q].z, Pa.z, __builtin_fmaf(Q[q].y, Pa.y, Q[q].x * Pa.x));
            m0[q] = fmaxf(m0[q], __builtin_fmaf(2.0f, ia, -Pa.w));
            const float ib = __builtin_fmaf(Q[q].z, Pb.z, __builtin_fmaf(Q[q].y, Pb.y, Q[q].x * Pb.x));
            m1[q] = fmaxf(m1[q], __builtin_fmaf(2.0f, ib, -Pb.w));
        }
    }
    float s[4];
#pragma unroll
    for (int q = 0; q < 4; ++q) s[q] = fmaxf(m0[q], m1[q]) + nxx[q];

    // ---- descending bitonic sort of lane maxima (4 queries interleaved); L = rank-15 ----
#pragma unroll
    for (int k = 2; k <= 64; k <<= 1) {
#pragma unroll
        for (int j = k >> 1; j > 0; j >>= 1) {
            const bool takeMax = ((lane & j) == 0) ^ ((lane & k) != 0);
#pragma unroll
            for (int q = 0; q < 4; ++q) {
                const float o = __shfl_xor(s[q], j);
                s[q] = takeMax ? fmaxf(s[q], o) : fminf(s[q], o);
            }
        }
    }
    float L[4];
#pragma unroll
    for (int q = 0; q < 4; ++q) L[q] = __shfl(s[q], 15);

    // ---- init survivor lists ----
#pragma unroll
    for (int q = 0; q < 4; ++q) { dv[wave][q][lane] = -3.0e38f; di[wave][q][lane] = 0x7FFFFFFF; }
    if (lane < 4) cnt[wave][lane] = 0;
    __syncthreads();

    // ---- pass 2: exact pd; compact survivors via LDS atomic ----
#pragma unroll 2
    for (int i = 0; i < 64; ++i) {
        const float4 P = xb[(i << 6) + lane];
        const int id = (i << 6) + lane;
#pragma unroll
        for (int q = 0; q < 4; ++q) {
            const float inner = __builtin_fmaf(Q[q].z, P.z, __builtin_fmaf(Q[q].y, P.y, __fmul_rn(Q[q].x, P.x)));
            const float v = __fsub_rn(__fadd_rn(nxx[q], __fmul_rn(2.0f, inner)), P.w);
            if (v >= L[q]) {
                const int pos = atomicAdd(&cnt[wave][q], 1);
                if (pos < 64) { dv[wave][q][pos] = v; di[wave][q][pos] = id; }
            }
        }
    }
    __syncthreads();

    int S[4];
#pragma unroll
    for (int q = 0; q < 4; ++q) S[q] = cnt[wave][q];

    float pv[4]; int pi[4];
#pragma unroll
    for (int q = 0; q < 4; ++q) { pv[q] = dv[wave][q][lane]; pi[q] = di[wave][q][lane]; }

    // ---- bitonic pair-sort (value desc, index asc), 4 queries interleaved ----
#pragma unroll
    for (int k = 2; k <= 64; k <<= 1) {
#pragma unroll
        for (int j = k >> 1; j > 0; j >>= 1) {
            const bool takeHi = ((lane & j) == 0) ^ ((lane & k) != 0);
#pragma unroll
            for (int q = 0; q < 4; ++q) {
                const float ov = __shfl_xor(pv[q], j);
                const int   oi = __shfl_xor(pi[q], j);
                const bool ogt = (ov > pv[q]) || (ov == pv[q] && oi < pi[q]);
                if (takeHi == ogt) { pv[q] = ov; pi[q] = oi; }
            }
        }
    }

    // ---- output (lane k holds k-th neighbor); rare fallback if filter failed ----
#pragma unroll
    for (int q = 0; q < 4; ++q) {
        int sel = pi[q];
        if (S[q] < 16 || S[q] > 64) {
            // exhaustive recompute rescan: select iteratively under (value desc, index asc)
            float prevv = 3.0e38f; int previ = -1;
            for (int it = 0; it < Kn; ++it) {
                float bv = -3.0e38f; int bm = 0x7FFFFFFF;
                for (int i = 0; i < 64; ++i) {
                    const float4 P = xb[(i << 6) + lane];
                    const int id = (i << 6) + lane;
                    const float inner = __builtin_fmaf(Q[q].z, P.z, __builtin_fmaf(Q[q].y, P.y, __fmul_rn(Q[q].x, P.x)));
                    const float v = __fsub_rn(__fadd_rn(nxx[q], __fmul_rn(2.0f, inner)), P.w);
                    const bool after = (v < prevv) || (v == prevv && id > previ);
                    if (after && (v > bv || (v == bv && id < bm))) { bv = v; bm = id; }
                }
#pragma unroll
                for (int off = 32; off; off >>= 1) {
                    const float ov = __shfl_xor(bv, off);
                    const int   om = __shfl_xor(bm, off);
                    if (ov > bv || (ov == bv && om < bm)) { bv = ov; bm = om; }
                }
                if (lane == it) sel = bm;
                prevv = bv; previ = bm;
            }
        }
        if (lane < Kn) idxout[(size_t)(rbase + q) * Kn + lane] = sel;
    }
}

// ---------------- Kernel B0: M = Wq^T @ Wk, v = bq @ Wk, u = Wq^T @ bk, w = bq . bk ----------------
__global__ __launch_bounds__(128) void prep_kernel(const float* __restrict__ Wq, const float* __restrict__ bq,
                                                   const float* __restrict__ Wk, const float* __restrict__ bk,
                                                   float* __restrict__ M, float* __restrict__ u,
                                                   float* __restrict__ v, float* __restrict__ w)
{
    const int dp = blockIdx.x;   // d'
    const int d  = threadIdx.x;  // d
    float acc = 0.f;
    for (int e = 0; e < Dn; ++e) acc = fmaf(Wq[e * Dn + dp], Wk[e * Dn + d], acc);
    M[dp * Dn + d] = acc;
    if (d == 0) {
        float a = 0.f;
        for (int e = 0; e < Dn; ++e) a = fmaf(Wq[e * Dn + dp], bk[e], a);
        u[dp] = a;
    }
    if (dp == 0) {
        float a = 0.f;
        for (int e = 0; e < Dn; ++e) a = fmaf(bq[e], Wk[e * Dn + d], a);
        v[d] = a;
        if (d == 0) {
            float s = 0.f;
            for (int e = 0; e < Dn; ++e) s = fmaf(bq[e], bk[e], s);
            *w = s;
        }
    }
}

// ---------------- Kernel B: t = concat @ M + v  ([32768x128] @ [128x128]) ----------------
__global__ __launch_bounds__(256) void tmat_kernel(const float* __restrict__ concat, const float* __restrict__ M,
                                                   const float* __restrict__ vvec, float* __restrict__ tout)
{
    __shared__ float As[64][33];
    __shared__ float Ms[32][128];
    const int tid = threadIdx.x;
    const int row0 = blockIdx.x * 64;
    const int tx = tid & 15;   // col group: cols tx*8 .. tx*8+7
    const int ty = tid >> 4;   // row group: rows ty*4 .. ty*4+3
    float acc[4][8];
#pragma unroll
    for (int r = 0; r < 4; ++r)
#pragma unroll
        for (int j = 0; j < 8; ++j) acc[r][j] = 0.f;

    for (int kc = 0; kc < 4; ++kc) {
        const int k0 = kc * 32;
        __syncthreads();
#pragma unroll
        for (int p = 0; p < 8; ++p) {
            const int e = p * 256 + tid;
            const int r = e >> 5, kk = e & 31;
            As[r][kk] = concat[(size_t)(row0 + r) * Dn + k0 + kk];
        }
#pragma unroll
        for (int p = 0; p < 16; ++p) {
            const int e = p * 256 + tid;
            const int kk = e >> 7, dd = e & 127;
            Ms[kk][dd] = M[(k0 + kk) * Dn + dd];
        }
        __syncthreads();
#pragma unroll
        for (int k = 0; k < 32; ++k) {
            const float4 mA = *(const float4*)(&Ms[k][tx * 8]);
            const float4 mB = *(const float4*)(&Ms[k][tx * 8 + 4]);
            const float mj[8] = {mA.x, mA.y, mA.z, mA.w, mB.x, mB.y, mB.z, mB.w};
#pragma unroll
            for (int r = 0; r < 4; ++r) {
                const float av = As[ty * 4 + r][k];
#pragma unroll
                for (int j = 0; j < 8; ++j) acc[r][j] = fmaf(av, mj[j], acc[r][j]);
            }
        }
    }
    float vv[8];
#pragma unroll
    for (int j = 0; j < 8; ++j) vv[j] = vvec[tx * 8 + j];
#pragma unroll
    for (int r = 0; r < 4; ++r)
#pragma unroll
        for (int j = 0; j < 8; ++j)
            tout[(size_t)(row0 + ty * 4 + r) * Dn + tx * 8 + j] = acc[r][j] + vv[j];
}

// ---------------- Kernel C: transpose fp4_features [B,C,N] -> featT [B,N,C] ----------------
__global__ __launch_bounds__(256) void transpose_kernel(const float* __restrict__ feat, float* __restrict__ featT)
{
    __shared__ float tile[32][33];
    const int n0 = blockIdx.x * 32;
    const int c0 = blockIdx.y * 32;
    const int b  = blockIdx.z;
    const int ln = threadIdx.x & 31, lg = threadIdx.x >> 5;  // 8 row-groups
    const float* fb = feat + (size_t)b * Cn * Nn;
#pragma unroll
    for (int p = 0; p < 4; ++p) {
        const int c = lg + p * 8;
        tile[c][ln] = fb[(size_t)(c0 + c) * Nn + n0 + ln];
    }
    __syncthreads();
    float* ob = featT + (size_t)b * Nn * Cn;
#pragma unroll
    for (int p = 0; p < 4; ++p) {
        const int nn = lg + p * 8;
        ob[(size_t)(n0 + nn) * Cn + c0 + ln] = tile[ln][nn];
    }
}

// ---------------- Kernel D: fused scores + softmax + neighbor-feature aggregation ----------------
__global__ __launch_bounds__(256) void fused_kernel(const float* __restrict__ concat, const float* __restrict__ tmat,
                                                    const float* __restrict__ featT, const int* __restrict__ knn,
                                                    const float* __restrict__ u, const float* __restrict__ wscal,
                                                    float* __restrict__ out)
{
    __shared__ float outs[16][256];
    const int wave = threadIdx.x >> 6;
    const int lane = threadIdx.x & 63;
    const int rbase = blockIdx.x * 16;
    const float u0 = u[lane], u1 = u[lane + 64];
    const float w = *wscal;
    const float scale = 0.08838834764831845f;  // 1/sqrt(128)

    for (int pt = 0; pt < 4; ++pt) {
        const int row = rbase + wave * 4 + pt;
        const int b = row >> 12;
        const float* cb = concat + (size_t)row * Dn;
        const float t0 = tmat[(size_t)row * Dn + lane];
        const float t1 = tmat[(size_t)row * Dn + 64 + lane];
        const float cn0 = cb[lane], cn1 = cb[64 + lane];

        float pz = t0 * cn0 + t1 * cn1;   // -> z = t . c_n
        float ps = cn0 * u0 + cn1 * u1;   // -> s0 = c_n . u + w
#pragma unroll
        for (int off = 32; off; off >>= 1) {
            pz += __shfl_xor(pz, off);
            ps += __shfl_xor(ps, off);
        }
        const float zz = pz;
        const float s0 = ps + w;

        int myidx = 0;
        if (lane < Kn) myidx = knn[row * Kn + lane];

        float p[16];
#pragma unroll
        for (int j = 0; j < 16; ++j) {
            const int ij = __shfl(myidx, j);
            const float* cj = concat + ((size_t)b * Nn + ij) * Dn;
            p[j] = t0 * cj[lane] + t1 * cj[64 + lane];
        }
#pragma unroll
        for (int off = 32; off; off >>= 1) {
#pragma unroll
            for (int j = 0; j < 16; ++j) p[j] += __shfl_xor(p[j], off);
        }

        float mx = -3.0e38f;
#pragma unroll
        for (int j = 0; j < 16; ++j) {
            p[j] = (p[j] - zz + s0) * scale;
            mx = fmaxf(mx, p[j]);
        }
        float sum = 0.f;
#pragma unroll
        for (int j = 0; j < 16; ++j) { p[j] = __expf(p[j] - mx); sum += p[j]; }
        const float inv = 1.0f / sum;

        float4 acc = make_float4(0.f, 0.f, 0.f, 0.f);
#pragma unroll
        for (int j = 0; j < 16; ++j) {
            const int ij = __shfl(myidx, j);
            const float4 f = *(const float4*)(&featT[((size_t)b * Nn + ij) * Cn + lane * 4]);
            const float a = p[j] * inv;
            acc.x = fmaf(a, f.x, acc.x);
            acc.y = fmaf(a, f.y, acc.y);
            acc.z = fmaf(a, f.z, acc.z);
            acc.w = fmaf(a, f.w, acc.w);
        }
        *(float4*)(&outs[wave * 4 + pt][lane * 4]) = acc;
    }
    __syncthreads();

    const int b = rbase >> 12;
    const int n0 = rbase & (Nn - 1);
#pragma unroll
    for (int p2 = 0; p2 < 16; ++p2) {
        const int c  = (threadIdx.x >> 4) + p2 * 16;
        const int nn = threadIdx.x & 15;
        out[((size_t)b * Cn + c) * Nn + n0 + nn] = outs[nn][c];
    }
}

extern "C" void kernel_launch(void* const* d_in, const int* in_sizes, int n_in,
                              void* d_out, int out_size, void* d_ws, size_t ws_size,
                              hipStream_t stream) {
    const float* xyz    = (const float*)d_in[0];   // [B,N,3]
    const float* feat   = (const float*)d_in[1];   // [B,C,N]
    const float* concat = (const float*)d_in[2];   // [B,N,D]
    const float* Wq     = (const float*)d_in[3];
    const float* bq     = (const float*)d_in[4];
    const float* Wk     = (const float*)d_in[5];
    const float* bk     = (const float*)d_in[6];
    float* out = (float*)d_out;
    float* ws  = (float*)d_ws;

    // workspace layout (float units), offsets 16B-aligned
    float*  M     = ws;                 // 16384
    float*  u     = ws + 16384;         // 128
    float*  v     = ws + 16512;         // 128
    float*  w     = ws + 16640;         // 1
    int*    idx   = (int*)(ws + 16704); // 32768*16 ints
    float*  t     = ws + 540992;        // 32768*128
    float*  featT = ws + 4735296;       // 8*4096*256
    float4* xyzw  = (float4*)(ws + 13123904); // 32768 float4 = 131072 floats
    // total: 13,254,976 floats = 53.0 MB

    hipLaunchKernelGGL(pack_kernel,      dim3(128),        dim3(256), 0, stream, xyz, xyzw);
    hipLaunchKernelGGL(prep_kernel,      dim3(128),        dim3(128), 0, stream, Wq, bq, Wk, bk, M, u, v, w);
    hipLaunchKernelGGL(knn_kernel,       dim3(2048),       dim3(256), 0, stream, xyzw, idx);
    hipLaunchKernelGGL(tmat_kernel,      dim3(512),        dim3(256), 0, stream, concat, M, v, t);
    hipLaunchKernelGGL(transpose_kernel, dim3(128, 8, 8),  dim3(256), 0, stream, feat, featT);
    hipLaunchKernelGGL(fused_kernel,     dim3(2048),       dim3(256), 0, stream, concat, t, featT, idx, u, w, out);
}

// Round 7
// 403.112 us; speedup vs baseline: 2.4121x; 2.4121x over previous
//
#include <hip/hip_runtime.h>
#include <stdint.h>

constexpr int Bn = 8, Nn = 4096, Dn = 128, Cn = 256, Kn = 16;

// ---------------- Kernel A0: pack xyz -> float4 (x,y,z,xx), xx = ((x*x)+(y*y))+(z*z) exact ----------------
__global__ __launch_bounds__(256) void pack_kernel(const float* __restrict__ xyz, float4* __restrict__ xyzw)
{
    const int p = blockIdx.x * 256 + threadIdx.x;   // 32768 points
    const float x = xyz[p * 3 + 0], y = xyz[p * 3 + 1], z = xyz[p * 3 + 2];
    const float xx = __fadd_rn(__fadd_rn(__fmul_rn(x, x), __fmul_rn(y, y)), __fmul_rn(z, z));
    xyzw[p] = make_float4(x, y, z, xx);
}

// exact pd, shared by both passes (and the reference-matching formula from rounds 3-5):
// pd = ((-xx_n) + 2*inner) - xx_m,  inner = fma(qz,pz, fma(qy,py, mul_rn(qx,px)))
__device__ __forceinline__ float pd_exact(const float4 Q, const float nxx, const float4 P)
{
    const float inner = __builtin_fmaf(Q.z, P.z, __builtin_fmaf(Q.y, P.y, __fmul_rn(Q.x, P.x)));
    return __fsub_rn(__fadd_rn(nxx, __fmul_rn(2.0f, inner)), P.w);
}

// ---------------- Kernel A: exact KNN, fp32, two-pass threshold filter + bitonic pair-sort ----------------
// 4 query rows per wave (16 per block) amortize the candidate sweep 4x.
// Pass 1: per-lane max of EXACT pd per query (same rounding as pass 2 -- this is what
// guarantees S >= 16: the 16 lanes with max >= L each hold a distinct point >= L).
// L = 16th-largest lane max (bitonic over lanes). Pass 2: recompute exact pd, compact
// survivors (v >= L) to dense LDS via atomicAdd (order irrelevant: sort key
// (value desc, index asc) is a strict total order). 21-step bitonic pair-sort leaves
// the k-th neighbor in lane k. S<16 or S>64 (prob ~0) -> exhaustive rescan fallback.
__global__ __launch_bounds__(256) void knn_kernel(const float4* __restrict__ xyzw, int* __restrict__ idxout)
{
    __shared__ float dv[4][4][64];
    __shared__ int   di[4][4][64];
    __shared__ int   cnt[4][4];
    const int wave = threadIdx.x >> 6;
    const int lane = threadIdx.x & 63;
    const int rbase = blockIdx.x * 16 + wave * 4;      // 4 consecutive rows, same batch
    const float4* xb = xyzw + (size_t)(rbase >> 12) * Nn;
    const int n0 = rbase & (Nn - 1);

    float4 Q[4];
    float nxx[4];
#pragma unroll
    for (int q = 0; q < 4; ++q) { Q[q] = xb[n0 + q]; nxx[q] = -Q[q].w; }

    // ---- pass 1: per-lane max of exact pd per query ----
    float m0[4], m1[4];
#pragma unroll
    for (int q = 0; q < 4; ++q) { m0[q] = -3.0e38f; m1[q] = -3.0e38f; }
    for (int i = 0; i < 64; i += 2) {
        const float4 Pa = xb[(i << 6) + lane];
        const float4 Pb = xb[((i + 1) << 6) + lane];
#pragma unroll
        for (int q = 0; q < 4; ++q) {
            m0[q] = fmaxf(m0[q], pd_exact(Q[q], nxx[q], Pa));
            m1[q] = fmaxf(m1[q], pd_exact(Q[q], nxx[q], Pb));
        }
    }
    float s[4];
#pragma unroll
    for (int q = 0; q < 4; ++q) s[q] = fmaxf(m0[q], m1[q]);

    // ---- descending bitonic sort of lane maxima (4 queries interleaved); L = rank-15 ----
#pragma unroll
    for (int k = 2; k <= 64; k <<= 1) {
#pragma unroll
        for (int j = k >> 1; j > 0; j >>= 1) {
            const bool takeMax = ((lane & j) == 0) ^ ((lane & k) != 0);
#pragma unroll
            for (int q = 0; q < 4; ++q) {
                const float o = __shfl_xor(s[q], j);
                s[q] = takeMax ? fmaxf(s[q], o) : fminf(s[q], o);
            }
        }
    }
    float L[4];
#pragma unroll
    for (int q = 0; q < 4; ++q) L[q] = __shfl(s[q], 15);

    // ---- init survivor lists ----
#pragma unroll
    for (int q = 0; q < 4; ++q) { dv[wave][q][lane] = -3.0e38f; di[wave][q][lane] = 0x7FFFFFFF; }
    if (lane < 4) cnt[wave][lane] = 0;
    __syncthreads();

    // ---- pass 2: exact pd; compact survivors via LDS atomic ----
#pragma unroll 2
    for (int i = 0; i < 64; ++i) {
        const float4 P = xb[(i << 6) + lane];
        const int id = (i << 6) + lane;
#pragma unroll
        for (int q = 0; q < 4; ++q) {
            const float v = pd_exact(Q[q], nxx[q], P);
            if (v >= L[q]) {
                const int pos = atomicAdd(&cnt[wave][q], 1);
                if (pos < 64) { dv[wave][q][pos] = v; di[wave][q][pos] = id; }
            }
        }
    }
    __syncthreads();

    int S[4];
#pragma unroll
    for (int q = 0; q < 4; ++q) S[q] = cnt[wave][q];

    float pv[4]; int pi[4];
#pragma unroll
    for (int q = 0; q < 4; ++q) { pv[q] = dv[wave][q][lane]; pi[q] = di[wave][q][lane]; }

    // ---- bitonic pair-sort (value desc, index asc), 4 queries interleaved ----
#pragma unroll
    for (int k = 2; k <= 64; k <<= 1) {
#pragma unroll
        for (int j = k >> 1; j > 0; j >>= 1) {
            const bool takeHi = ((lane & j) == 0) ^ ((lane & k) != 0);
#pragma unroll
            for (int q = 0; q < 4; ++q) {
                const float ov = __shfl_xor(pv[q], j);
                const int   oi = __shfl_xor(pi[q], j);
                const bool ogt = (ov > pv[q]) || (ov == pv[q] && oi < pi[q]);
                if (takeHi == ogt) { pv[q] = ov; pi[q] = oi; }
            }
        }
    }

    // ---- output (lane k holds k-th neighbor); safety fallback (never taken: S>=16 by construction) ----
#pragma unroll
    for (int q = 0; q < 4; ++q) {
        int sel = pi[q];
        if (S[q] < 16 || S[q] > 64) {
            float prevv = 3.0e38f; int previ = -1;
            for (int it = 0; it < Kn; ++it) {
                float bv = -3.0e38f; int bm = 0x7FFFFFFF;
                for (int i = 0; i < 64; ++i) {
                    const float4 P = xb[(i << 6) + lane];
                    const int id = (i << 6) + lane;
                    const float v = pd_exact(Q[q], nxx[q], P);
                    const bool after = (v < prevv) || (v == prevv && id > previ);
                    if (after && (v > bv || (v == bv && id < bm))) { bv = v; bm = id; }
                }
#pragma unroll
                for (int off = 32; off; off >>= 1) {
                    const float ov = __shfl_xor(bv, off);
                    const int   om = __shfl_xor(bm, off);
                    if (ov > bv || (ov == bv && om < bm)) { bv = ov; bm = om; }
                }
                if (lane == it) sel = bm;
                prevv = bv; previ = bm;
            }
        }
        if (lane < Kn) idxout[(size_t)(rbase + q) * Kn + lane] = sel;
    }
}

// ---------------- Kernel B0: M = Wq^T @ Wk, v = bq @ Wk, u = Wq^T @ bk, w = bq . bk ----------------
__global__ __launch_bounds__(128) void prep_kernel(const float* __restrict__ Wq, const float* __restrict__ bq,
                                                   const float* __restrict__ Wk, const float* __restrict__ bk,
                                                   float* __restrict__ M, float* __restrict__ u,
                                                   float* __restrict__ v, float* __restrict__ w)
{
    const int dp = blockIdx.x;   // d'
    const int d  = threadIdx.x;  // d
    float acc = 0.f;
    for (int e = 0; e < Dn; ++e) acc = fmaf(Wq[e * Dn + dp], Wk[e * Dn + d], acc);
    M[dp * Dn + d] = acc;
    if (d == 0) {
        float a = 0.f;
        for (int e = 0; e < Dn; ++e) a = fmaf(Wq[e * Dn + dp], bk[e], a);
        u[dp] = a;
    }
    if (dp == 0) {
        float a = 0.f;
        for (int e = 0; e < Dn; ++e) a = fmaf(bq[e], Wk[e * Dn + d], a);
        v[d] = a;
        if (d == 0) {
            float s = 0.f;
            for (int e = 0; e < Dn; ++e) s = fmaf(bq[e], bk[e], s);
            *w = s;
        }
    }
}

// ---------------- Kernel B: t = concat @ M + v  ([32768x128] @ [128x128]) ----------------
__global__ __launch_bounds__(256) void tmat_kernel(const float* __restrict__ concat, const float* __restrict__ M,
                                                   const float* __restrict__ vvec, float* __restrict__ tout)
{
    __shared__ float As[64][33];
    __shared__ float Ms[32][128];
    const int tid = threadIdx.x;
    const int row0 = blockIdx.x * 64;
    const int tx = tid & 15;   // col group: cols tx*8 .. tx*8+7
    const int ty = tid >> 4;   // row group: rows ty*4 .. ty*4+3
    float acc[4][8];
#pragma unroll
    for (int r = 0; r < 4; ++r)
#pragma unroll
        for (int j = 0; j < 8; ++j) acc[r][j] = 0.f;

    for (int kc = 0; kc < 4; ++kc) {
        const int k0 = kc * 32;
        __syncthreads();
#pragma unroll
        for (int p = 0; p < 8; ++p) {
            const int e = p * 256 + tid;
            const int r = e >> 5, kk = e & 31;
            As[r][kk] = concat[(size_t)(row0 + r) * Dn + k0 + kk];
        }
#pragma unroll
        for (int p = 0; p < 16; ++p) {
            const int e = p * 256 + tid;
            const int kk = e >> 7, dd = e & 127;
            Ms[kk][dd] = M[(k0 + kk) * Dn + dd];
        }
        __syncthreads();
#pragma unroll
        for (int k = 0; k < 32; ++k) {
            const float4 mA = *(const float4*)(&Ms[k][tx * 8]);
            const float4 mB = *(const float4*)(&Ms[k][tx * 8 + 4]);
            const float mj[8] = {mA.x, mA.y, mA.z, mA.w, mB.x, mB.y, mB.z, mB.w};
#pragma unroll
            for (int r = 0; r < 4; ++r) {
                const float av = As[ty * 4 + r][k];
#pragma unroll
                for (int j = 0; j < 8; ++j) acc[r][j] = fmaf(av, mj[j], acc[r][j]);
            }
        }
    }
    float vv[8];
#pragma unroll
    for (int j = 0; j < 8; ++j) vv[j] = vvec[tx * 8 + j];
#pragma unroll
    for (int r = 0; r < 4; ++r)
#pragma unroll
        for (int j = 0; j < 8; ++j)
            tout[(size_t)(row0 + ty * 4 + r) * Dn + tx * 8 + j] = acc[r][j] + vv[j];
}

// ---------------- Kernel C: transpose fp4_features [B,C,N] -> featT [B,N,C] ----------------
__global__ __launch_bounds__(256) void transpose_kernel(const float* __restrict__ feat, float* __restrict__ featT)
{
    __shared__ float tile[32][33];
    const int n0 = blockIdx.x * 32;
    const int c0 = blockIdx.y * 32;
    const int b  = blockIdx.z;
    const int ln = threadIdx.x & 31, lg = threadIdx.x >> 5;  // 8 row-groups
    const float* fb = feat + (size_t)b * Cn * Nn;
#pragma unroll
    for (int p = 0; p < 4; ++p) {
        const int c = lg + p * 8;
        tile[c][ln] = fb[(size_t)(c0 + c) * Nn + n0 + ln];
    }
    __syncthreads();
    float* ob = featT + (size_t)b * Nn * Cn;
#pragma unroll
    for (int p = 0; p < 4; ++p) {
        const int nn = lg + p * 8;
        ob[(size_t)(n0 + nn) * Cn + c0 + ln] = tile[ln][nn];
    }
}

// ---------------- Kernel D: fused scores + softmax + neighbor-feature aggregation ----------------
__global__ __launch_bounds__(256) void fused_kernel(const float* __restrict__ concat, const float* __restrict__ tmat,
                                                    const float* __restrict__ featT, const int* __restrict__ knn,
                                                    const float* __restrict__ u, const float* __restrict__ wscal,
                                                    float* __restrict__ out)
{
    __shared__ float outs[16][256];
    const int wave = threadIdx.x >> 6;
    const int lane = threadIdx.x & 63;
    const int rbase = blockIdx.x * 16;
    const float u0 = u[lane], u1 = u[lane + 64];
    const float w = *wscal;
    const float scale = 0.08838834764831845f;  // 1/sqrt(128)

    for (int pt = 0; pt < 4; ++pt) {
        const int row = rbase + wave * 4 + pt;
        const int b = row >> 12;
        const float* cb = concat + (size_t)row * Dn;
        const float t0 = tmat[(size_t)row * Dn + lane];
        const float t1 = tmat[(size_t)row * Dn + 64 + lane];
        const float cn0 = cb[lane], cn1 = cb[64 + lane];

        float pz = t0 * cn0 + t1 * cn1;   // -> z = t . c_n
        float ps = cn0 * u0 + cn1 * u1;   // -> s0 = c_n . u + w
#pragma unroll
        for (int off = 32; off; off >>= 1) {
            pz += __shfl_xor(pz, off);
            ps += __shfl_xor(ps, off);
        }
        const float zz = pz;
        const float s0 = ps + w;

        int myidx = 0;
        if (lane < Kn) myidx = knn[row * Kn + lane];

        float p[16];
#pragma unroll
        for (int j = 0; j < 16; ++j) {
            const int ij = __shfl(myidx, j);
            const float* cj = concat + ((size_t)b * Nn + ij) * Dn;
            p[j] = t0 * cj[lane] + t1 * cj[64 + lane];
        }
#pragma unroll
        for (int off = 32; off; off >>= 1) {
#pragma unroll
            for (int j = 0; j < 16; ++j) p[j] += __shfl_xor(p[j], off);
        }

        float mx = -3.0e38f;
#pragma unroll
        for (int j = 0; j < 16; ++j) {
            p[j] = (p[j] - zz + s0) * scale;
            mx = fmaxf(mx, p[j]);
        }
        float sum = 0.f;
#pragma unroll
        for (int j = 0; j < 16; ++j) { p[j] = __expf(p[j] - mx); sum += p[j]; }
        const float inv = 1.0f / sum;

        float4 acc = make_float4(0.f, 0.f, 0.f, 0.f);
#pragma unroll
        for (int j = 0; j < 16; ++j) {
            const int ij = __shfl(myidx, j);
            const float4 f = *(const float4*)(&featT[((size_t)b * Nn + ij) * Cn + lane * 4]);
            const float a = p[j] * inv;
            acc.x = fmaf(a, f.x, acc.x);
            acc.y = fmaf(a, f.y, acc.y);
            acc.z = fmaf(a, f.z, acc.z);
            acc.w = fmaf(a, f.w, acc.w);
        }
        *(float4*)(&outs[wave * 4 + pt][lane * 4]) = acc;
    }
    __syncthreads();

    const int b = rbase >> 12;
    const int n0 = rbase & (Nn - 1);
#pragma unroll
    for (int p2 = 0; p2 < 16; ++p2) {
        const int c  = (threadIdx.x >> 4) + p2 * 16;
        const int nn = threadIdx.x & 15;
        out[((size_t)b * Cn + c) * Nn + n0 + nn] = outs[nn][c];
    }
}

extern "C" void kernel_launch(void* const* d_in, const int* in_sizes, int n_in,
                              void* d_out, int out_size, void* d_ws, size_t ws_size,
                              hipStream_t stream) {
    const float* xyz    = (const float*)d_in[0];   // [B,N,3]
    const float* feat   = (const float*)d_in[1];   // [B,C,N]
    const float* concat = (const float*)d_in[2];   // [B,N,D]
    const float* Wq     = (const float*)d_in[3];
    const float* bq     = (const float*)d_in[4];
    const float* Wk     = (const float*)d_in[5];
    const float* bk     = (const float*)d_in[6];
    float* out = (float*)d_out;
    float* ws  = (float*)d_ws;

    // workspace layout (float units), offsets 16B-aligned
    float*  M     = ws;                 // 16384
    float*  u     = ws + 16384;         // 128
    float*  v     = ws + 16512;         // 128
    float*  w     = ws + 16640;         // 1
    int*    idx   = (int*)(ws + 16704); // 32768*16 ints
    float*  t     = ws + 540992;        // 32768*128
    float*  featT = ws + 4735296;       // 8*4096*256
    float4* xyzw  = (float4*)(ws + 13123904); // 32768 float4 = 131072 floats
    // total: 13,254,976 floats = 53.0 MB

    hipLaunchKernelGGL(pack_kernel,      dim3(128),        dim3(256), 0, stream, xyz, xyzw);
    hipLaunchKernelGGL(prep_kernel,      dim3(128),        dim3(128), 0, stream, Wq, bq, Wk, bk, M, u, v, w);
    hipLaunchKernelGGL(knn_kernel,       dim3(2048),       dim3(256), 0, stream, xyzw, idx);
    hipLaunchKernelGGL(tmat_kernel,      dim3(512),        dim3(256), 0, stream, concat, M, v, t);
    hipLaunchKernelGGL(transpose_kernel, dim3(128, 8, 8),  dim3(256), 0, stream, feat, featT);
    hipLaunchKernelGGL(fused_kernel,     dim3(2048),       dim3(256), 0, stream, concat, t, featT, idx, u, w, out);
}

// Round 8
// 279.124 us; speedup vs baseline: 3.4835x; 1.4442x over previous
//
#include <hip/hip_runtime.h>
#include <stdint.h>

constexpr int Bn = 8, Nn = 4096, Dn = 128, Cn = 256, Kn = 16;

// ---------------- Kernel A0: pack xyz -> float4 (x,y,z,xx), xx = ((x*x)+(y*y))+(z*z) exact ----------------
__global__ __launch_bounds__(256) void pack_kernel(const float* __restrict__ xyz, float4* __restrict__ xyzw)
{
    const int p = blockIdx.x * 256 + threadIdx.x;   // 32768 points
    const float x = xyz[p * 3 + 0], y = xyz[p * 3 + 1], z = xyz[p * 3 + 2];
    const float xx = __fadd_rn(__fadd_rn(__fmul_rn(x, x), __fmul_rn(y, y)), __fmul_rn(z, z));
    xyzw[p] = make_float4(x, y, z, xx);
}

// exact pd (the reference-matching formula from rounds 3-7):
// pd = ((-xx_n) + 2*inner) - xx_m,  inner = fma(qz,pz, fma(qy,py, mul_rn(qx,px)))
__device__ __forceinline__ float pd_exact(const float4 Q, const float nxx, const float4 P)
{
    const float inner = __builtin_fmaf(Q.z, P.z, __builtin_fmaf(Q.y, P.y, __fmul_rn(Q.x, P.x)));
    return __fsub_rn(__fadd_rn(nxx, __fmul_rn(2.0f, inner)), P.w);
}

// ---------------- Kernel A: exact KNN from LDS-staged point cloud ----------------
// 512-thread blocks (8 waves x 4 queries = 32 rows/block). The block stages the full
// 4096-point batch (64KB) into LDS once; both passes then read LDS only.
// Pass 1: per-lane max of exact pd (same bits as pass 2 => S >= 16 guaranteed).
// L = 16th-largest lane max via interleaved bitonic. Pass 2: recompute exact pd,
// compact survivor INDICES to LDS via atomicAdd (order irrelevant under the strict
// (value desc, index asc) sort key). Values re-derived from LDS at sort-init
// (identical bits). 21-step bitonic pair-sort leaves k-th neighbor in lane k.
// S<16 or S>64 (prob ~0) -> exhaustive rescan from LDS (always correct).
__global__ __launch_bounds__(512, 4) void knn_kernel(const float4* __restrict__ xyzw, int* __restrict__ idxout)
{
    __shared__ float4 pts[Nn];        // 65536 B
    __shared__ int    di[8][4][64];   // 8192 B
    __shared__ int    cnt[8][4];
    const int tid  = threadIdx.x;
    const int wave = tid >> 6;
    const int lane = tid & 63;
    const int rbase = blockIdx.x * 32 + wave * 4;     // 4 consecutive rows, one batch per block
    const float4* xb = xyzw + (size_t)(rbase >> 12) * Nn;

    // ---- stage the whole batch point cloud into LDS (coalesced) ----
#pragma unroll
    for (int t = 0; t < 8; ++t) pts[tid + t * 512] = xb[tid + t * 512];
    if (lane < 4) { cnt[wave][lane] = 0; }
#pragma unroll
    for (int q = 0; q < 4; ++q) di[wave][q][lane] = 0x7FFFFFFF;
    __syncthreads();

    const int n0 = rbase & (Nn - 1);
    float4 Q[4]; float nxx[4];
#pragma unroll
    for (int q = 0; q < 4; ++q) { Q[q] = pts[n0 + q]; nxx[q] = -Q[q].w; }

    // ---- pass 1: per-lane max of exact pd per query (from LDS) ----
    float m0[4], m1[4];
#pragma unroll
    for (int q = 0; q < 4; ++q) { m0[q] = -3.0e38f; m1[q] = -3.0e38f; }
    for (int i = 0; i < 64; i += 2) {
        const float4 Pa = pts[(i << 6) + lane];
        const float4 Pb = pts[((i + 1) << 6) + lane];
#pragma unroll
        for (int q = 0; q < 4; ++q) {
            m0[q] = fmaxf(m0[q], pd_exact(Q[q], nxx[q], Pa));
            m1[q] = fmaxf(m1[q], pd_exact(Q[q], nxx[q], Pb));
        }
    }
    float s[4];
#pragma unroll
    for (int q = 0; q < 4; ++q) s[q] = fmaxf(m0[q], m1[q]);

    // ---- descending bitonic sort of lane maxima (4 queries interleaved); L = rank-15 ----
#pragma unroll
    for (int k = 2; k <= 64; k <<= 1) {
#pragma unroll
        for (int j = k >> 1; j > 0; j >>= 1) {
            const bool takeMax = ((lane & j) == 0) ^ ((lane & k) != 0);
#pragma unroll
            for (int q = 0; q < 4; ++q) {
                const float o = __shfl_xor(s[q], j);
                s[q] = takeMax ? fmaxf(s[q], o) : fminf(s[q], o);
            }
        }
    }
    float L[4];
#pragma unroll
    for (int q = 0; q < 4; ++q) L[q] = __shfl(s[q], 15);

    // ---- pass 2: exact pd from LDS; compact survivor indices via LDS atomic ----
#pragma unroll 2
    for (int i = 0; i < 64; ++i) {
        const float4 P = pts[(i << 6) + lane];
        const int id = (i << 6) + lane;
#pragma unroll
        for (int q = 0; q < 4; ++q) {
            const float v = pd_exact(Q[q], nxx[q], P);
            if (v >= L[q]) {
                const int pos = atomicAdd(&cnt[wave][q], 1);
                if (pos < 64) di[wave][q][pos] = id;
            }
        }
    }
    __syncthreads();

    int S[4];
#pragma unroll
    for (int q = 0; q < 4; ++q) S[q] = cnt[wave][q];

    // sort-init: re-derive values from LDS (identical bits to pass 1/2)
    float pv[4]; int pi[4];
#pragma unroll
    for (int q = 0; q < 4; ++q) {
        pi[q] = di[wave][q][lane];
        pv[q] = (pi[q] != 0x7FFFFFFF) ? pd_exact(Q[q], nxx[q], pts[pi[q]]) : -3.0e38f;
    }

    // ---- bitonic pair-sort (value desc, index asc), 4 queries interleaved ----
#pragma unroll
    for (int k = 2; k <= 64; k <<= 1) {
#pragma unroll
        for (int j = k >> 1; j > 0; j >>= 1) {
            const bool takeHi = ((lane & j) == 0) ^ ((lane & k) != 0);
#pragma unroll
            for (int q = 0; q < 4; ++q) {
                const float ov = __shfl_xor(pv[q], j);
                const int   oi = __shfl_xor(pi[q], j);
                const bool ogt = (ov > pv[q]) || (ov == pv[q] && oi < pi[q]);
                if (takeHi == ogt) { pv[q] = ov; pi[q] = oi; }
            }
        }
    }

    // ---- output (lane k holds k-th neighbor); safety fallback (dead: S>=16 by construction) ----
#pragma unroll
    for (int q = 0; q < 4; ++q) {
        int sel = pi[q];
        if (S[q] < 16 || S[q] > 64) {
            float prevv = 3.0e38f; int previ = -1;
            for (int it = 0; it < Kn; ++it) {
                float bv = -3.0e38f; int bm = 0x7FFFFFFF;
                for (int i = 0; i < 64; ++i) {
                    const float4 P = pts[(i << 6) + lane];
                    const int id = (i << 6) + lane;
                    const float v = pd_exact(Q[q], nxx[q], P);
                    const bool after = (v < prevv) || (v == prevv && id > previ);
                    if (after && (v > bv || (v == bv && id < bm))) { bv = v; bm = id; }
                }
#pragma unroll
                for (int off = 32; off; off >>= 1) {
                    const float ov = __shfl_xor(bv, off);
                    const int   om = __shfl_xor(bm, off);
                    if (ov > bv || (ov == bv && om < bm)) { bv = ov; bm = om; }
                }
                if (lane == it) sel = bm;
                prevv = bv; previ = bm;
            }
        }
        if (lane < Kn) idxout[(size_t)(rbase + q) * Kn + lane] = sel;
    }
}

// ---------------- Kernel B0: M = Wq^T @ Wk, v = bq @ Wk, u = Wq^T @ bk, w = bq . bk ----------------
__global__ __launch_bounds__(128) void prep_kernel(const float* __restrict__ Wq, const float* __restrict__ bq,
                                                   const float* __restrict__ Wk, const float* __restrict__ bk,
                                                   float* __restrict__ M, float* __restrict__ u,
                                                   float* __restrict__ v, float* __restrict__ w)
{
    const int dp = blockIdx.x;   // d'
    const int d  = threadIdx.x;  // d
    float acc = 0.f;
    for (int e = 0; e < Dn; ++e) acc = fmaf(Wq[e * Dn + dp], Wk[e * Dn + d], acc);
    M[dp * Dn + d] = acc;
    if (d == 0) {
        float a = 0.f;
        for (int e = 0; e < Dn; ++e) a = fmaf(Wq[e * Dn + dp], bk[e], a);
        u[dp] = a;
    }
    if (dp == 0) {
        float a = 0.f;
        for (int e = 0; e < Dn; ++e) a = fmaf(bq[e], Wk[e * Dn + d], a);
        v[d] = a;
        if (d == 0) {
            float s = 0.f;
            for (int e = 0; e < Dn; ++e) s = fmaf(bq[e], bk[e], s);
            *w = s;
        }
    }
}

// ---------------- Kernel B: t = concat @ M + v  ([32768x128] @ [128x128]) ----------------
__global__ __launch_bounds__(256) void tmat_kernel(const float* __restrict__ concat, const float* __restrict__ M,
                                                   const float* __restrict__ vvec, float* __restrict__ tout)
{
    __shared__ float As[64][33];
    __shared__ float Ms[32][128];
    const int tid = threadIdx.x;
    const int row0 = blockIdx.x * 64;
    const int tx = tid & 15;   // col group: cols tx*8 .. tx*8+7
    const int ty = tid >> 4;   // row group: rows ty*4 .. ty*4+3
    float acc[4][8];
#pragma unroll
    for (int r = 0; r < 4; ++r)
#pragma unroll
        for (int j = 0; j < 8; ++j) acc[r][j] = 0.f;

    for (int kc = 0; kc < 4; ++kc) {
        const int k0 = kc * 32;
        __syncthreads();
#pragma unroll
        for (int p = 0; p < 8; ++p) {
            const int e = p * 256 + tid;
            const int r = e >> 5, kk = e & 31;
            As[r][kk] = concat[(size_t)(row0 + r) * Dn + k0 + kk];
        }
#pragma unroll
        for (int p = 0; p < 16; ++p) {
            const int e = p * 256 + tid;
            const int kk = e >> 7, dd = e & 127;
            Ms[kk][dd] = M[(k0 + kk) * Dn + dd];
        }
        __syncthreads();
#pragma unroll
        for (int k = 0; k < 32; ++k) {
            const float4 mA = *(const float4*)(&Ms[k][tx * 8]);
            const float4 mB = *(const float4*)(&Ms[k][tx * 8 + 4]);
            const float mj[8] = {mA.x, mA.y, mA.z, mA.w, mB.x, mB.y, mB.z, mB.w};
#pragma unroll
            for (int r = 0; r < 4; ++r) {
                const float av = As[ty * 4 + r][k];
#pragma unroll
                for (int j = 0; j < 8; ++j) acc[r][j] = fmaf(av, mj[j], acc[r][j]);
            }
        }
    }
    float vv[8];
#pragma unroll
    for (int j = 0; j < 8; ++j) vv[j] = vvec[tx * 8 + j];
#pragma unroll
    for (int r = 0; r < 4; ++r)
#pragma unroll
        for (int j = 0; j < 8; ++j)
            tout[(size_t)(row0 + ty * 4 + r) * Dn + tx * 8 + j] = acc[r][j] + vv[j];
}

// ---------------- Kernel C: transpose fp4_features [B,C,N] -> featT [B,N,C] ----------------
__global__ __launch_bounds__(256) void transpose_kernel(const float* __restrict__ feat, float* __restrict__ featT)
{
    __shared__ float tile[32][33];
    const int n0 = blockIdx.x * 32;
    const int c0 = blockIdx.y * 32;
    const int b  = blockIdx.z;
    const int ln = threadIdx.x & 31, lg = threadIdx.x >> 5;  // 8 row-groups
    const float* fb = feat + (size_t)b * Cn * Nn;
#pragma unroll
    for (int p = 0; p < 4; ++p) {
        const int c = lg + p * 8;
        tile[c][ln] = fb[(size_t)(c0 + c) * Nn + n0 + ln];
    }
    __syncthreads();
    float* ob = featT + (size_t)b * Nn * Cn;
#pragma unroll
    for (int p = 0; p < 4; ++p) {
        const int nn = lg + p * 8;
        ob[(size_t)(n0 + nn) * Cn + c0 + ln] = tile[ln][nn];
    }
}

// ---------------- Kernel D: fused scores + softmax + neighbor-feature aggregation ----------------
__global__ __launch_bounds__(256) void fused_kernel(const float* __restrict__ concat, const float* __restrict__ tmat,
                                                    const float* __restrict__ featT, const int* __restrict__ knn,
                                                    const float* __restrict__ u, const float* __restrict__ wscal,
                                                    float* __restrict__ out)
{
    __shared__ float outs[16][256];
    const int wave = threadIdx.x >> 6;
    const int lane = threadIdx.x & 63;
    const int rbase = blockIdx.x * 16;
    const float u0 = u[lane], u1 = u[lane + 64];
    const float w = *wscal;
    const float scale = 0.08838834764831845f;  // 1/sqrt(128)

    for (int pt = 0; pt < 4; ++pt) {
        const int row = rbase + wave * 4 + pt;
        const int b = row >> 12;
        const float* cb = concat + (size_t)row * Dn;
        const float t0 = tmat[(size_t)row * Dn + lane];
        const float t1 = tmat[(size_t)row * Dn + 64 + lane];
        const float cn0 = cb[lane], cn1 = cb[64 + lane];

        float pz = t0 * cn0 + t1 * cn1;   // -> z = t . c_n
        float ps = cn0 * u0 + cn1 * u1;   // -> s0 = c_n . u + w
#pragma unroll
        for (int off = 32; off; off >>= 1) {
            pz += __shfl_xor(pz, off);
            ps += __shfl_xor(ps, off);
        }
        const float zz = pz;
        const float s0 = ps + w;

        int myidx = 0;
        if (lane < Kn) myidx = knn[row * Kn + lane];

        float p[16];
#pragma unroll
        for (int j = 0; j < 16; ++j) {
            const int ij = __shfl(myidx, j);
            const float* cj = concat + ((size_t)b * Nn + ij) * Dn;
            p[j] = t0 * cj[lane] + t1 * cj[64 + lane];
        }
#pragma unroll
        for (int off = 32; off; off >>= 1) {
#pragma unroll
            for (int j = 0; j < 16; ++j) p[j] += __shfl_xor(p[j], off);
        }

        float mx = -3.0e38f;
#pragma unroll
        for (int j = 0; j < 16; ++j) {
            p[j] = (p[j] - zz + s0) * scale;
            mx = fmaxf(mx, p[j]);
        }
        float sum = 0.f;
#pragma unroll
        for (int j = 0; j < 16; ++j) { p[j] = __expf(p[j] - mx); sum += p[j]; }
        const float inv = 1.0f / sum;

        float4 acc = make_float4(0.f, 0.f, 0.f, 0.f);
#pragma unroll
        for (int j = 0; j < 16; ++j) {
            const int ij = __shfl(myidx, j);
            const float4 f = *(const float4*)(&featT[((size_t)b * Nn + ij) * Cn + lane * 4]);
            const float a = p[j] * inv;
            acc.x = fmaf(a, f.x, acc.x);
            acc.y = fmaf(a, f.y, acc.y);
            acc.z = fmaf(a, f.z, acc.z);
            acc.w = fmaf(a, f.w, acc.w);
        }
        *(float4*)(&outs[wave * 4 + pt][lane * 4]) = acc;
    }
    __syncthreads();

    const int b = rbase >> 12;
    const int n0 = rbase & (Nn - 1);
#pragma unroll
    for (int p2 = 0; p2 < 16; ++p2) {
        const int c  = (threadIdx.x >> 4) + p2 * 16;
        const int nn = threadIdx.x & 15;
        out[((size_t)b * Cn + c) * Nn + n0 + nn] = outs[nn][c];
    }
}

extern "C" void kernel_launch(void* const* d_in, const int* in_sizes, int n_in,
                              void* d_out, int out_size, void* d_ws, size_t ws_size,
                              hipStream_t stream) {
    const float* xyz    = (const float*)d_in[0];   // [B,N,3]
    const float* feat   = (const float*)d_in[1];   // [B,C,N]
    const float* concat = (const float*)d_in[2];   // [B,N,D]
    const float* Wq     = (const float*)d_in[3];
    const float* bq     = (const float*)d_in[4];
    const float* Wk     = (const float*)d_in[5];
    const float* bk     = (const float*)d_in[6];
    float* out = (float*)d_out;
    float* ws  = (float*)d_ws;

    // workspace layout (float units), offsets 16B-aligned
    float*  M     = ws;                 // 16384
    float*  u     = ws + 16384;         // 128
    float*  v     = ws + 16512;         // 128
    float*  w     = ws + 16640;         // 1
    int*    idx   = (int*)(ws + 16704); // 32768*16 ints
    float*  t     = ws + 540992;        // 32768*128
    float*  featT = ws + 4735296;       // 8*4096*256
    float4* xyzw  = (float4*)(ws + 13123904); // 32768 float4 = 131072 floats
    // total: 13,254,976 floats = 53.0 MB

    hipLaunchKernelGGL(pack_kernel,      dim3(128),        dim3(256), 0, stream, xyz, xyzw);
    hipLaunchKernelGGL(prep_kernel,      dim3(128),        dim3(128), 0, stream, Wq, bq, Wk, bk, M, u, v, w);
    hipLaunchKernelGGL(knn_kernel,       dim3(1024),       dim3(512), 0, stream, xyzw, idx);
    hipLaunchKernelGGL(tmat_kernel,      dim3(512),        dim3(256), 0, stream, concat, M, v, t);
    hipLaunchKernelGGL(transpose_kernel, dim3(128, 8, 8),  dim3(256), 0, stream, feat, featT);
    hipLaunchKernelGGL(fused_kernel,     dim3(2048),       dim3(256), 0, stream, concat, t, featT, idx, u, w, out);
}

// Round 9
// 266.988 us; speedup vs baseline: 3.6418x; 1.0455x over previous
//
#include <hip/hip_runtime.h>
#include <stdint.h>

constexpr int Bn = 8, Nn = 4096, Dn = 128, Cn = 256, Kn = 16;

// ---------------- Kernel A0: pack xyz -> float4 (x,y,z,xx), xx = ((x*x)+(y*y))+(z*z) exact ----------------
__global__ __launch_bounds__(256) void pack_kernel(const float* __restrict__ xyz, float4* __restrict__ xyzw)
{
    const int p = blockIdx.x * 256 + threadIdx.x;   // 32768 points
    const float x = xyz[p * 3 + 0], y = xyz[p * 3 + 1], z = xyz[p * 3 + 2];
    const float xx = __fadd_rn(__fadd_rn(__fmul_rn(x, x), __fmul_rn(y, y)), __fmul_rn(z, z));
    xyzw[p] = make_float4(x, y, z, xx);
}

// exact pd (the reference-matching formula from rounds 3-8):
// pd = ((-xx_n) + 2*inner) - xx_m,  inner = fma(qz,pz, fma(qy,py, mul_rn(qx,px)))
__device__ __forceinline__ float pd_exact(const float4 Q, const float nxx, const float4 P)
{
    const float inner = __builtin_fmaf(Q.z, P.z, __builtin_fmaf(Q.y, P.y, __fmul_rn(Q.x, P.x)));
    return __fsub_rn(__fadd_rn(nxx, __fmul_rn(2.0f, inner)), P.w);
}

// ---------------- Kernel A: exact KNN from LDS-staged point cloud ----------------
// 512-thread blocks (8 waves x 4 queries = 32 rows/block). The block stages the full
// 4096-point batch (64KB) into LDS once; both passes then read LDS only.
// launch_bounds(512, 2): VGPR ceiling 128 (NOT 64 -- round 8's (512,4) forced VGPR=64
// and spilled ~450B/thread to scratch: 233MB HBM writes). LDS caps us at 2 blocks/CU.
__global__ __launch_bounds__(512, 2) void knn_kernel(const float4* __restrict__ xyzw, int* __restrict__ idxout)
{
    __shared__ float4 pts[Nn];        // 65536 B
    __shared__ int    di[8][4][64];   // 8192 B
    __shared__ int    cnt[8][4];
    const int tid  = threadIdx.x;
    const int wave = tid >> 6;
    const int lane = tid & 63;
    const int rbase = blockIdx.x * 32 + wave * 4;     // 4 consecutive rows, one batch per block
    const float4* xb = xyzw + (size_t)(rbase >> 12) * Nn;

    // ---- stage the whole batch point cloud into LDS (coalesced) ----
#pragma unroll
    for (int t = 0; t < 8; ++t) pts[tid + t * 512] = xb[tid + t * 512];
    if (lane < 4) { cnt[wave][lane] = 0; }
#pragma unroll
    for (int q = 0; q < 4; ++q) di[wave][q][lane] = 0x7FFFFFFF;
    __syncthreads();

    const int n0 = rbase & (Nn - 1);
    float4 Q[4]; float nxx[4];
#pragma unroll
    for (int q = 0; q < 4; ++q) { Q[q] = pts[n0 + q]; nxx[q] = -Q[q].w; }

    // ---- pass 1: per-lane max of exact pd per query (from LDS) ----
    float m0[4], m1[4];
#pragma unroll
    for (int q = 0; q < 4; ++q) { m0[q] = -3.0e38f; m1[q] = -3.0e38f; }
    for (int i = 0; i < 64; i += 2) {
        const float4 Pa = pts[(i << 6) + lane];
        const float4 Pb = pts[((i + 1) << 6) + lane];
#pragma unroll
        for (int q = 0; q < 4; ++q) {
            m0[q] = fmaxf(m0[q], pd_exact(Q[q], nxx[q], Pa));
            m1[q] = fmaxf(m1[q], pd_exact(Q[q], nxx[q], Pb));
        }
    }
    float s[4];
#pragma unroll
    for (int q = 0; q < 4; ++q) s[q] = fmaxf(m0[q], m1[q]);

    // ---- descending bitonic sort of lane maxima (4 queries interleaved); L = rank-15 ----
#pragma unroll
    for (int k = 2; k <= 64; k <<= 1) {
#pragma unroll
        for (int j = k >> 1; j > 0; j >>= 1) {
            const bool takeMax = ((lane & j) == 0) ^ ((lane & k) != 0);
#pragma unroll
            for (int q = 0; q < 4; ++q) {
                const float o = __shfl_xor(s[q], j);
                s[q] = takeMax ? fmaxf(s[q], o) : fminf(s[q], o);
            }
        }
    }
    float L[4];
#pragma unroll
    for (int q = 0; q < 4; ++q) L[q] = __shfl(s[q], 15);

    // ---- pass 2: exact pd from LDS; compact survivor indices via LDS atomic ----
#pragma unroll 2
    for (int i = 0; i < 64; ++i) {
        const float4 P = pts[(i << 6) + lane];
        const int id = (i << 6) + lane;
#pragma unroll
        for (int q = 0; q < 4; ++q) {
            const float v = pd_exact(Q[q], nxx[q], P);
            if (v >= L[q]) {
                const int pos = atomicAdd(&cnt[wave][q], 1);
                if (pos < 64) di[wave][q][pos] = id;
            }
        }
    }
    __syncthreads();

    int S[4];
#pragma unroll
    for (int q = 0; q < 4; ++q) S[q] = cnt[wave][q];

    // sort-init: re-derive values from LDS (identical bits to pass 1/2)
    float pv[4]; int pi[4];
#pragma unroll
    for (int q = 0; q < 4; ++q) {
        pi[q] = di[wave][q][lane];
        pv[q] = (pi[q] != 0x7FFFFFFF) ? pd_exact(Q[q], nxx[q], pts[pi[q]]) : -3.0e38f;
    }

    // ---- bitonic pair-sort (value desc, index asc), 4 queries interleaved ----
#pragma unroll
    for (int k = 2; k <= 64; k <<= 1) {
#pragma unroll
        for (int j = k >> 1; j > 0; j >>= 1) {
            const bool takeHi = ((lane & j) == 0) ^ ((lane & k) != 0);
#pragma unroll
            for (int q = 0; q < 4; ++q) {
                const float ov = __shfl_xor(pv[q], j);
                const int   oi = __shfl_xor(pi[q], j);
                const bool ogt = (ov > pv[q]) || (ov == pv[q] && oi < pi[q]);
                if (takeHi == ogt) { pv[q] = ov; pi[q] = oi; }
            }
        }
    }

    // ---- output (lane k holds k-th neighbor); safety fallback (dead: S>=16 by construction) ----
#pragma unroll
    for (int q = 0; q < 4; ++q) {
        int sel = pi[q];
        if (S[q] < 16 || S[q] > 64) {
            float prevv = 3.0e38f; int previ = -1;
            for (int it = 0; it < Kn; ++it) {
                float bv = -3.0e38f; int bm = 0x7FFFFFFF;
                for (int i = 0; i < 64; ++i) {
                    const float4 P = pts[(i << 6) + lane];
                    const int id = (i << 6) + lane;
                    const float v = pd_exact(Q[q], nxx[q], P);
                    const bool after = (v < prevv) || (v == prevv && id > previ);
                    if (after && (v > bv || (v == bv && id < bm))) { bv = v; bm = id; }
                }
#pragma unroll
                for (int off = 32; off; off >>= 1) {
                    const float ov = __shfl_xor(bv, off);
                    const int   om = __shfl_xor(bm, off);
                    if (ov > bv || (ov == bv && om < bm)) { bv = ov; bm = om; }
                }
                if (lane == it) sel = bm;
                prevv = bv; previ = bm;
            }
        }
        if (lane < Kn) idxout[(size_t)(rbase + q) * Kn + lane] = sel;
    }
}

// ---------------- Kernel B0: M = Wq^T @ Wk, v = bq @ Wk, u = Wq^T @ bk, w = bq . bk ----------------
__global__ __launch_bounds__(128) void prep_kernel(const float* __restrict__ Wq, const float* __restrict__ bq,
                                                   const float* __restrict__ Wk, const float* __restrict__ bk,
                                                   float* __restrict__ M, float* __restrict__ u,
                                                   float* __restrict__ v, float* __restrict__ w)
{
    const int dp = blockIdx.x;   // d'
    const int d  = threadIdx.x;  // d
    float acc = 0.f;
    for (int e = 0; e < Dn; ++e) acc = fmaf(Wq[e * Dn + dp], Wk[e * Dn + d], acc);
    M[dp * Dn + d] = acc;
    if (d == 0) {
        float a = 0.f;
        for (int e = 0; e < Dn; ++e) a = fmaf(Wq[e * Dn + dp], bk[e], a);
        u[dp] = a;
    }
    if (dp == 0) {
        float a = 0.f;
        for (int e = 0; e < Dn; ++e) a = fmaf(bq[e], Wk[e * Dn + d], a);
        v[d] = a;
        if (d == 0) {
            float s = 0.f;
            for (int e = 0; e < Dn; ++e) s = fmaf(bq[e], bk[e], s);
            *w = s;
        }
    }
}

// ---------------- Kernel B: t = concat @ M + v  ([32768x128] @ [128x128]) ----------------
__global__ __launch_bounds__(256) void tmat_kernel(const float* __restrict__ concat, const float* __restrict__ M,
                                                   const float* __restrict__ vvec, float* __restrict__ tout)
{
    __shared__ float As[64][33];
    __shared__ float Ms[32][128];
    const int tid = threadIdx.x;
    const int row0 = blockIdx.x * 64;
    const int tx = tid & 15;   // col group: cols tx*8 .. tx*8+7
    const int ty = tid >> 4;   // row group: rows ty*4 .. ty*4+3
    float acc[4][8];
#pragma unroll
    for (int r = 0; r < 4; ++r)
#pragma unroll
        for (int j = 0; j < 8; ++j) acc[r][j] = 0.f;

    for (int kc = 0; kc < 4; ++kc) {
        const int k0 = kc * 32;
        __syncthreads();
#pragma unroll
        for (int p = 0; p < 8; ++p) {
            const int e = p * 256 + tid;
            const int r = e >> 5, kk = e & 31;
            As[r][kk] = concat[(size_t)(row0 + r) * Dn + k0 + kk];
        }
#pragma unroll
        for (int p = 0; p < 16; ++p) {
            const int e = p * 256 + tid;
            const int kk = e >> 7, dd = e & 127;
            Ms[kk][dd] = M[(k0 + kk) * Dn + dd];
        }
        __syncthreads();
#pragma unroll
        for (int k = 0; k < 32; ++k) {
            const float4 mA = *(const float4*)(&Ms[k][tx * 8]);
            const float4 mB = *(const float4*)(&Ms[k][tx * 8 + 4]);
            const float mj[8] = {mA.x, mA.y, mA.z, mA.w, mB.x, mB.y, mB.z, mB.w};
#pragma unroll
            for (int r = 0; r < 4; ++r) {
                const float av = As[ty * 4 + r][k];
#pragma unroll
                for (int j = 0; j < 8; ++j) acc[r][j] = fmaf(av, mj[j], acc[r][j]);
            }
        }
    }
    float vv[8];
#pragma unroll
    for (int j = 0; j < 8; ++j) vv[j] = vvec[tx * 8 + j];
#pragma unroll
    for (int r = 0; r < 4; ++r)
#pragma unroll
        for (int j = 0; j < 8; ++j)
            tout[(size_t)(row0 + ty * 4 + r) * Dn + tx * 8 + j] = acc[r][j] + vv[j];
}

// ---------------- Kernel C: transpose fp4_features [B,C,N] -> featT [B,N,C] ----------------
__global__ __launch_bounds__(256) void transpose_kernel(const float* __restrict__ feat, float* __restrict__ featT)
{
    __shared__ float tile[32][33];
    const int n0 = blockIdx.x * 32;
    const int c0 = blockIdx.y * 32;
    const int b  = blockIdx.z;
    const int ln = threadIdx.x & 31, lg = threadIdx.x >> 5;  // 8 row-groups
    const float* fb = feat + (size_t)b * Cn * Nn;
#pragma unroll
    for (int p = 0; p < 4; ++p) {
        const int c = lg + p * 8;
        tile[c][ln] = fb[(size_t)(c0 + c) * Nn + n0 + ln];
    }
    __syncthreads();
    float* ob = featT + (size_t)b * Nn * Cn;
#pragma unroll
    for (int p = 0; p < 4; ++p) {
        const int nn = lg + p * 8;
        ob[(size_t)(n0 + nn) * Cn + c0 + ln] = tile[ln][nn];
    }
}

// ---------------- Kernel D: fused scores + softmax + neighbor-feature aggregation ----------------
__global__ __launch_bounds__(256) void fused_kernel(const float* __restrict__ concat, const float* __restrict__ tmat,
                                                    const float* __restrict__ featT, const int* __restrict__ knn,
                                                    const float* __restrict__ u, const float* __restrict__ wscal,
                                                    float* __restrict__ out)
{
    __shared__ float outs[16][256];
    const int wave = threadIdx.x >> 6;
    const int lane = threadIdx.x & 63;
    const int rbase = blockIdx.x * 16;
    const float u0 = u[lane], u1 = u[lane + 64];
    const float w = *wscal;
    const float scale = 0.08838834764831845f;  // 1/sqrt(128)

    for (int pt = 0; pt < 4; ++pt) {
        const int row = rbase + wave * 4 + pt;
        const int b = row >> 12;
        const float* cb = concat + (size_t)row * Dn;
        const float t0 = tmat[(size_t)row * Dn + lane];
        const float t1 = tmat[(size_t)row * Dn + 64 + lane];
        const float cn0 = cb[lane], cn1 = cb[64 + lane];

        float pz = t0 * cn0 + t1 * cn1;   // -> z = t . c_n
        float ps = cn0 * u0 + cn1 * u1;   // -> s0 = c_n . u + w
#pragma unroll
        for (int off = 32; off; off >>= 1) {
            pz += __shfl_xor(pz, off);
            ps += __shfl_xor(ps, off);
        }
        const float zz = pz;
        const float s0 = ps + w;

        int myidx = 0;
        if (lane < Kn) myidx = knn[row * Kn + lane];

        float p[16];
#pragma unroll
        for (int j = 0; j < 16; ++j) {
            const int ij = __shfl(myidx, j);
            const float* cj = concat + ((size_t)b * Nn + ij) * Dn;
            p[j] = t0 * cj[lane] + t1 * cj[64 + lane];
        }
#pragma unroll
        for (int off = 32; off; off >>= 1) {
#pragma unroll
            for (int j = 0; j < 16; ++j) p[j] += __shfl_xor(p[j], off);
        }

        float mx = -3.0e38f;
#pragma unroll
        for (int j = 0; j < 16; ++j) {
            p[j] = (p[j] - zz + s0) * scale;
            mx = fmaxf(mx, p[j]);
        }
        float sum = 0.f;
#pragma unroll
        for (int j = 0; j < 16; ++j) { p[j] = __expf(p[j] - mx); sum += p[j]; }
        const float inv = 1.0f / sum;

        float4 acc = make_float4(0.f, 0.f, 0.f, 0.f);
#pragma unroll
        for (int j = 0; j < 16; ++j) {
            const int ij = __shfl(myidx, j);
            const float4 f = *(const float4*)(&featT[((size_t)b * Nn + ij) * Cn + lane * 4]);
            const float a = p[j] * inv;
            acc.x = fmaf(a, f.x, acc.x);
            acc.y = fmaf(a, f.y, acc.y);
            acc.z = fmaf(a, f.z, acc.z);
            acc.w = fmaf(a, f.w, acc.w);
        }
        *(float4*)(&outs[wave * 4 + pt][lane * 4]) = acc;
    }
    __syncthreads();

    const int b = rbase >> 12;
    const int n0 = rbase & (Nn - 1);
#pragma unroll
    for (int p2 = 0; p2 < 16; ++p2) {
        const int c  = (threadIdx.x >> 4) + p2 * 16;
        const int nn = threadIdx.x & 15;
        out[((size_t)b * Cn + c) * Nn + n0 + nn] = outs[nn][c];
    }
}

extern "C" void kernel_launch(void* const* d_in, const int* in_sizes, int n_in,
                              void* d_out, int out_size, void* d_ws, size_t ws_size,
                              hipStream_t stream) {
    const float* xyz    = (const float*)d_in[0];   // [B,N,3]
    const float* feat   = (const float*)d_in[1];   // [B,C,N]
    const float* concat = (const float*)d_in[2];   // [B,N,D]
    const float* Wq     = (const float*)d_in[3];
    const float* bq     = (const float*)d_in[4];
    const float* Wk     = (const float*)d_in[5];
    const float* bk     = (const float*)d_in[6];
    float* out = (float*)d_out;
    float* ws  = (float*)d_ws;

    // workspace layout (float units), offsets 16B-aligned
    float*  M     = ws;                 // 16384
    float*  u     = ws + 16384;         // 128
    float*  v     = ws + 16512;         // 128
    float*  w     = ws + 16640;         // 1
    int*    idx   = (int*)(ws + 16704); // 32768*16 ints
    float*  t     = ws + 540992;        // 32768*128
    float*  featT = ws + 4735296;       // 8*4096*256
    float4* xyzw  = (float4*)(ws + 13123904); // 32768 float4 = 131072 floats
    // total: 13,254,976 floats = 53.0 MB

    hipLaunchKernelGGL(pack_kernel,      dim3(128),        dim3(256), 0, stream, xyz, xyzw);
    hipLaunchKernelGGL(prep_kernel,      dim3(128),        dim3(128), 0, stream, Wq, bq, Wk, bk, M, u, v, w);
    hipLaunchKernelGGL(knn_kernel,       dim3(1024),       dim3(512), 0, stream, xyzw, idx);
    hipLaunchKernelGGL(tmat_kernel,      dim3(512),        dim3(256), 0, stream, concat, M, v, t);
    hipLaunchKernelGGL(transpose_kernel, dim3(128, 8, 8),  dim3(256), 0, stream, feat, featT);
    hipLaunchKernelGGL(fused_kernel,     dim3(2048),       dim3(256), 0, stream, concat, t, featT, idx, u, w, out);
}